// Round 4
// baseline (1030.249 us; speedup 1.0000x reference)
//
#include <hip/hip_runtime.h>

typedef unsigned short u16;
typedef unsigned int u32;
typedef __attribute__((ext_vector_type(8))) short short8;
typedef __attribute__((ext_vector_type(4))) float f32x4;

// ---------- bf16 helpers (RNE) ----------
__device__ __forceinline__ float b2f(u16 h) {
  union { u32 u; float f; } v; v.u = ((u32)h) << 16; return v.f;
}
__device__ __forceinline__ u16 f2b(float f) {
  union { float f; u32 u; } v; v.f = f;
  u32 u = v.u;
  u += 0x7fffu + ((u >> 16) & 1u);
  return (u16)(u >> 16);
}
__device__ __forceinline__ short8 ld8f(const float* p) {  // 8 f32 -> 8 bf16
  short8 r;
  #pragma unroll
  for (int i = 0; i < 8; i++) r[i] = (short)f2b(p[i]);
  return r;
}

// async global->LDS, 16B per lane. LDS dest is wave-uniform base + lane*16.
__device__ __forceinline__ void gload16(const u16* g, u16* lds_wave_base) {
  __builtin_amdgcn_global_load_lds(
      (const __attribute__((address_space(1))) u32*)g,
      (__attribute__((address_space(3))) u32*)lds_wave_base, 16, 0, 0);
}

// =====================================================================
// Generic NT GEMM: C[M,N] = A[M,K] * Bt[N,K]^T, fp32 accum, bf16 MFMA.
// A operand: f32 (AF32=1, converted during reg staging) or bf16 (AF32=0,
// staged via global_load_lds dwordx4 — m97 structure: the thread->LDS
// mapping row=t>>2, col=(t&3)*8 is byte-linear (t*16), matching the
// instruction's wave-uniform-base + lane*16 write pattern exactly).
// Bt/C always bf16. 128x128 C-tile, BK=32, 256 thr = 4 waves.
// EPI 0: C = bf16(acc)
// EPI 1: C = bf16(exp2(clamp(acc*expscale))); atomicAdd row sums into rowsum
// EPI 2: C = bf16(acc / rowsum[row] + Q[row,col])
// EPI 3: like EPI 0 but gate columns interleaved for the scan:
//        col<1024 unchanged; f_d (1024+d) -> 1024+2d ; r_d (2048+d) -> 1025+2d
// =====================================================================
template<int EPI, int AF32>
__global__ __launch_bounds__(256)
void gemm_nt(const void* __restrict__ Av, int lda, int a_boff,
             const u16* __restrict__ Bt, int ldb, int b_boff,
             u16* __restrict__ C, int ldc, int c_boff,
             int K,
             float* __restrict__ rowsum, int rs_boff,
             const u16* __restrict__ Q, int ldq, int q_boff,
             float expscale)
{
  __shared__ __align__(16) u16 As[128 * 32];
  __shared__ __align__(16) u16 Bs[128 * 32];
  const int z = blockIdx.z;
  Bt += (size_t)z * b_boff;
  C  += (size_t)z * c_boff;
  const int row0 = blockIdx.x * 128;
  const int col0 = blockIdx.y * 128;
  const int t = threadIdx.x;
  const int lane = t & 63, wave = t >> 6;
  const int wm = (wave >> 1) * 64, wn = (wave & 1) * 64;
  const int quad = lane >> 4, lrow = lane & 15;

  f32x4 acc[4][4] = {};

  const size_t a_base = (size_t)z * a_boff + (size_t)(row0 + (t >> 2)) * lda + (t & 3) * 8;
  const float* Agf = (const float*)Av + a_base;   // valid when AF32
  const u16*   Agh = (const u16*)Av + a_base;     // valid when !AF32
  const u16* Bg = Bt + (size_t)(col0 + (t >> 2)) * ldb + (t & 3) * 8;
  const size_t a64 = (size_t)64 * lda, b64 = (size_t)64 * ldb;
  // wave-uniform LDS staging bases (chunk0: rows 0..63; chunk1: rows 64..127)
  u16* AsW = As + wave * 512;
  u16* BsW = Bs + wave * 512;
  u16* AsP = As + t * 8;   // reg-staging path (AF32)
  u16* BsP = Bs + t * 8;

  for (int k0 = 0; k0 < K; k0 += 32) {
    if (AF32) {
      short8 ta0 = ld8f(Agf);
      short8 ta1 = ld8f(Agf + a64);
      Agf += 32;
      short8 tb0 = *(const short8*)Bg;
      short8 tb1 = *(const short8*)(Bg + b64);
      Bg += 32;
      __syncthreads();               // prev iteration's LDS reads complete
      *(short8*)AsP = ta0;
      *(short8*)(AsP + 2048) = ta1;
      *(short8*)BsP = tb0;
      *(short8*)(BsP + 2048) = tb1;
      __syncthreads();               // LDS tiles visible to all waves
    } else {
      __syncthreads();               // prev iteration's LDS reads complete
      gload16(Agh,       AsW);
      gload16(Agh + a64, AsW + 2048);
      gload16(Bg,        BsW);
      gload16(Bg + b64,  BsW + 2048);
      Agh += 32; Bg += 32;
      __syncthreads();               // implicit vmcnt(0) drain: tiles resident
    }
    short8 af[4], bfr[4];
    #pragma unroll
    for (int i = 0; i < 4; i++)
      af[i] = *(const short8*)(As + (wm + i * 16 + lrow) * 32 + quad * 8);
    #pragma unroll
    for (int j = 0; j < 4; j++)
      bfr[j] = *(const short8*)(Bs + (wn + j * 16 + lrow) * 32 + quad * 8);
    #pragma unroll
    for (int i = 0; i < 4; i++)
      #pragma unroll
      for (int j = 0; j < 4; j++)
        acc[i][j] = __builtin_amdgcn_mfma_f32_16x16x32_bf16(af[i], bfr[j], acc[i][j], 0, 0, 0);
  }

  // ---- epilogue. C/D layout: col = lane&15 (N side), row = quad*4 + reg (M side) ----
  if (EPI == 0) {
    #pragma unroll
    for (int i = 0; i < 4; i++)
      #pragma unroll
      for (int r = 0; r < 4; r++) {
        size_t grow = (size_t)(row0 + wm + i * 16 + quad * 4 + r) * ldc;
        #pragma unroll
        for (int j = 0; j < 4; j++)
          C[grow + col0 + wn + j * 16 + lrow] = f2b(acc[i][j][r]);
      }
  } else if (EPI == 1) {
    #pragma unroll
    for (int i = 0; i < 4; i++)
      #pragma unroll
      for (int r = 0; r < 4; r++) {
        int lr = row0 + wm + i * 16 + quad * 4 + r;
        size_t grow = (size_t)lr * ldc;
        float s = 0.f;
        #pragma unroll
        for (int j = 0; j < 4; j++) {
          float aa = acc[i][j][r] * expscale;
          aa = fminf(fmaxf(aa, -30.f), 30.f);
          float e = exp2f(aa);
          C[grow + col0 + wn + j * 16 + lrow] = f2b(e);
          s += e;
        }
        s += __shfl_xor(s, 1, 64);
        s += __shfl_xor(s, 2, 64);
        s += __shfl_xor(s, 4, 64);
        s += __shfl_xor(s, 8, 64);
        if (lrow == 0) atomicAdd(&rowsum[(size_t)z * rs_boff + lr], s);
      }
  } else if (EPI == 2) {
    const float* rs = rowsum + (size_t)z * rs_boff;
    const u16* Qb = Q + (size_t)z * q_boff;
    #pragma unroll
    for (int i = 0; i < 4; i++)
      #pragma unroll
      for (int r = 0; r < 4; r++) {
        int lr = row0 + wm + i * 16 + quad * 4 + r;
        float inv = 1.0f / rs[lr];
        size_t growc = (size_t)lr * ldc;
        size_t growq = (size_t)lr * ldq;
        #pragma unroll
        for (int j = 0; j < 4; j++) {
          int gcol = col0 + wn + j * 16 + lrow;
          float v = acc[i][j][r] * inv + b2f(Qb[growq + gcol]);
          C[growc + gcol] = f2b(v);
        }
      }
  } else {  // EPI == 3: gate-interleaved store for scan
    #pragma unroll
    for (int i = 0; i < 4; i++)
      #pragma unroll
      for (int r = 0; r < 4; r++) {
        size_t grow = (size_t)(row0 + wm + i * 16 + quad * 4 + r) * ldc;
        #pragma unroll
        for (int j = 0; j < 4; j++) {
          int gcol = col0 + wn + j * 16 + lrow;
          // tile is entirely on one side of 1024 (col0 multiple of 128), branch is uniform
          int ocol = gcol < 1024 ? gcol
                                 : 1024 + 2 * (gcol & 1023) + ((gcol >> 10) - 1);
          C[grow + ocol] = f2b(acc[i][j][r]);
        }
      }
  }
}

// =====================================================================
// Tiled transpose for weights: f32 in -> bf16 out, 64x64 tiles.
// =====================================================================
__global__ __launch_bounds__(256)
void transpose_f32_bf16(const float* __restrict__ in, int instride,
                        u16* __restrict__ out, int outstride)
{
  __shared__ u16 tile[64][66];
  const int r0 = blockIdx.x * 64, c0 = blockIdx.y * 64;
  const int tx = threadIdx.x & 63, ty = threadIdx.x >> 6;
  #pragma unroll
  for (int i = 0; i < 64; i += 4)
    tile[ty + i][tx] = f2b(in[(size_t)(r0 + ty + i) * instride + c0 + tx]);
  __syncthreads();
  #pragma unroll
  for (int i = 0; i < 64; i += 4)
    out[(size_t)(c0 + ty + i) * outstride + r0 + tx] = tile[tx][ty + i];
}

// =====================================================================
// Sequential SRU highway scan over L. One thread per (b,d) chain.
// U: bf16 [L*B, 3072] = [x_tilde(1024) | gates interleaved f0,r0,f1,r1,...]
// X,v,b,out: f32.
// 256 blocks x 64 thr: 1 wave per CU on all 256 CUs. PF=16 register FIFO,
// 4 vmem ops/iter -> consume-wait = vmcnt(61), expressible (max 63).
// =====================================================================
__global__ __launch_bounds__(64)
void scan_kernel(const u16* __restrict__ U, const float* __restrict__ X,
                 const float* __restrict__ V, const float* __restrict__ Bv,
                 float* __restrict__ out)
{
  const int idx = blockIdx.x * 64 + threadIdx.x;  // 0..16383
  const int d = idx & 1023, b = idx >> 10;
  const float nl2e = -1.4426950408889634f;
  const float vf = V[d],  vr = V[1024 + d];
  const float bf_ = Bv[d], br_ = Bv[1024 + d];
  const float pvf = nl2e * vf, pvr = nl2e * vr;

  constexpr int PF = 16;                 // prefetch depth (iterations)
  const size_t ustep = 16 * 3072;        // u16 elements per l-step
  const size_t gstep = 16 * 1536;        // u32 elements per l-step
  const size_t xstep = 16 * 1024;        // f32 elements per l-step

  const u16*  Uxt = U + (size_t)b * 3072 + d;                 // x_tilde
  const u32*  Ug  = (const u32*)(U + (size_t)b * 3072 + 1024) + d;  // (f,r) pair
  const float* Xp = X + (size_t)b * 1024 + d;
  float*       Op = out + (size_t)b * 1024 + d;

  u16 pxt[PF]; u32 pg[PF]; float pxr[PF];
  #pragma unroll
  for (int p = 0; p < PF; p++) {
    pxt[p] = Uxt[0];
    pg[p]  = Ug[0];
    pxr[p] = Xp[0];
    Uxt += ustep; Ug += gstep; Xp += xstep;
  }

  float c = 0.f;
  for (int l0 = 0; l0 < 2048 - PF; l0 += PF) {
    #pragma unroll
    for (int p = 0; p < PF; p++) {
      // consume slot p (iteration l0+p)
      float xt = b2f(pxt[p]);
      u32 g = pg[p];
      float fr = b2f((u16)(g & 0xffffu));
      float rr = b2f((u16)(g >> 16));
      float xr = pxr[p];
      // refill slot p (iteration l0+p+PF)
      pxt[p] = Uxt[0];
      pg[p]  = Ug[0];
      pxr[p] = Xp[0];
      Uxt += ustep; Ug += gstep; Xp += xstep;
      // gates: sigmoid(a) = rcp(1 + exp2(-log2e * a)); bias folded off-chain
      float ef = __builtin_amdgcn_exp2f(fmaf(pvf, c, nl2e * (fr + bf_)));
      float er = __builtin_amdgcn_exp2f(fmaf(pvr, c, nl2e * (rr + br_)));
      float fg = __builtin_amdgcn_rcpf(1.f + ef);
      float rg = __builtin_amdgcn_rcpf(1.f + er);
      c = fg * (c - xt) + xt;            // f*c + (1-f)*x_tilde
      float h = rg * (c - xr) + xr;      // r*c_new + (1-r)*x
      Op[0] = h; Op += xstep;
      __builtin_amdgcn_sched_barrier(0); // keep bodies in program order
    }
  }
  // tail: last PF iterations, compute-only (no OOB prefetch)
  #pragma unroll
  for (int p = 0; p < PF; p++) {
    float xt = b2f(pxt[p]);
    u32 g = pg[p];
    float fr = b2f((u16)(g & 0xffffu));
    float rr = b2f((u16)(g >> 16));
    float xr = pxr[p];
    float ef = __builtin_amdgcn_exp2f(fmaf(pvf, c, nl2e * (fr + bf_)));
    float er = __builtin_amdgcn_exp2f(fmaf(pvr, c, nl2e * (rr + br_)));
    float fg = __builtin_amdgcn_rcpf(1.f + ef);
    float rg = __builtin_amdgcn_rcpf(1.f + er);
    c = fg * (c - xt) + xt;
    float h = rg * (c - xr) + xr;
    Op[0] = h; Op += xstep;
  }
}

// =====================================================================
// Workspace layout (bytes) — total 240,254,976 B (~229.1 MB):
//  E    @ 0           134,217,728  bf16 [B,2048,2048]   } U aliases 0..192MB
//  q    @ 134,217,728  33,554,432  bf16 [32768,512]     } (all dead by U-GEMM)
//  vat  @ 167,772,160  33,554,432  bf16 [B,512,2048]    }
//  k    @ 201,326,592  33,554,432  bf16 [32768,512] (dead after E-GEMM)
//  ctxq @ 201,326,592  33,554,432  aliases k; outside U region
//  rsum @ 234,881,024     131,072  fp32 [B,2048]
//  W1t  @ 235,012,096   1,048,576  bf16 [512,1024]
//  W2t  @ 236,060,672   1,048,576  bf16 [1024,512]
//  W3t  @ 237,109,248   3,145,728  bf16 [3072,512]
//  U    @ 0           201,326,592  bf16 [32768,3072] (gate-interleaved)
// =====================================================================
extern "C" void kernel_launch(void* const* d_in, const int* in_sizes, int n_in,
                              void* d_out, int out_size, void* d_ws, size_t ws_size,
                              hipStream_t stream) {
  const float* x  = (const float*)d_in[0];
  const float* W1 = (const float*)d_in[1];
  const float* W2 = (const float*)d_in[2];
  const float* W3 = (const float*)d_in[3];
  const float* v  = (const float*)d_in[4];
  const float* bb = (const float*)d_in[5];
  float* out = (float*)d_out;
  char* ws = (char*)d_ws;

  u16*   E      = (u16*)(ws + 0);
  u16*   q      = (u16*)(ws + 134217728);
  u16*   vat    = (u16*)(ws + 167772160);
  u16*   kbuf   = (u16*)(ws + 201326592);
  u16*   ctxq   = (u16*)(ws + 201326592);  // aliases kbuf (dead by then)
  float* rowsum = (float*)(ws + 234881024);
  u16*   W1t    = (u16*)(ws + 235012096);
  u16*   W2t    = (u16*)(ws + 236060672);
  u16*   W3t    = (u16*)(ws + 237109248);
  u16*   U      = (u16*)(ws + 0);          // aliases E/q/vat (dead by then)

  hipMemsetAsync(rowsum, 0, 131072, stream);

  const dim3 blk(256);
  // weight transposes: W[K,N] f32 -> Wt[N,K] bf16 for NT GEMM
  transpose_f32_bf16<<<dim3(16, 8),  blk, 0, stream>>>(W1, 512,  W1t, 1024);
  transpose_f32_bf16<<<dim3(8, 16),  blk, 0, stream>>>(W2, 1024, W2t, 512);
  transpose_f32_bf16<<<dim3(8, 48),  blk, 0, stream>>>(W3, 3072, W3t, 512);

  // q = x @ W1 : M=32768 K=1024 N=512 (A is f32, converted in reg staging)
  gemm_nt<0, 1><<<dim3(256, 4, 1), blk, 0, stream>>>(x, 1024, 0, W1t, 1024, 0,
                                                     q, 512, 0, 1024,
                                                     nullptr, 0, nullptr, 0, 0, 0.f);
  // k = q @ W2[:, :512] : M=32768 K=512 N=512  (W2t rows 0..511)
  gemm_nt<0, 0><<<dim3(256, 4, 1), blk, 0, stream>>>(q, 512, 0, W2t, 512, 0,
                                                     kbuf, 512, 0, 512,
                                                     nullptr, 0, nullptr, 0, 0, 0.f);
  // vat_b[p][l] = sum_k W2t[512+p][k] * q_b[l][k]  (va^T, built transposed for free)
  // M=512 N=2048 K=512, z=B
  gemm_nt<0, 0><<<dim3(4, 16, 16), blk, 0, stream>>>(W2t + 262144, 512, 0, q, 8192, 512,
                                                     vat, 2048, 1048576, 512,
                                                     nullptr, 0, nullptr, 0, 0, 0.f);
  // E = exp(q_b @ k_b^T * scale), rowsum accumulated. M=N=2048 K=512, z=B
  const float expscale = 0.044194173824159216f * 1.4426950408889634f; // (1/sqrt(512))*log2(e)
  gemm_nt<1, 0><<<dim3(16, 16, 16), blk, 0, stream>>>(q, 8192, 512, kbuf, 8192, 512,
                                                      E, 2048, 4194304, 512,
                                                      rowsum, 2048, nullptr, 0, 0, expscale);
  // ctxq = E_b @ vat_b^T / rowsum + q : M=2048 N=512 K=2048, z=B
  gemm_nt<2, 0><<<dim3(16, 4, 16), blk, 0, stream>>>(E, 2048, 4194304, vat, 2048, 1048576,
                                                     ctxq, 8192, 512, 2048,
                                                     rowsum, 2048, q, 8192, 512, 0.f);
  // U = ctxq @ W3 : M=32768 K=512 N=3072, gate-interleaved store for scan
  gemm_nt<3, 0><<<dim3(256, 24, 1), blk, 0, stream>>>(ctxq, 512, 0, W3t, 512, 0,
                                                      U, 3072, 0, 512,
                                                      nullptr, 0, nullptr, 0, 0, 0.f);
  // highway recurrence: 256 blocks x 64 thr = 1 wave on each of 256 CUs
  scan_kernel<<<dim3(256, 1, 1), dim3(64), 0, stream>>>(U, x, v, bb, out);
}

// Round 6
// 999.046 us; speedup vs baseline: 1.0312x; 1.0312x over previous
//
#include <hip/hip_runtime.h>

typedef unsigned short u16;
typedef unsigned int u32;
typedef __attribute__((ext_vector_type(8))) short short8;
typedef __attribute__((ext_vector_type(4))) float f32x4;

// ---------- bf16 helpers (RNE) ----------
__device__ __forceinline__ float b2f(u16 h) {
  union { u32 u; float f; } v; v.u = ((u32)h) << 16; return v.f;
}
__device__ __forceinline__ u16 f2b(float f) {
  union { float f; u32 u; } v; v.f = f;
  u32 u = v.u;
  u += 0x7fffu + ((u >> 16) & 1u);
  return (u16)(u >> 16);
}
__device__ __forceinline__ short8 ld8f(const float* p) {  // 8 f32 -> 8 bf16
  short8 r;
  #pragma unroll
  for (int i = 0; i < 8; i++) r[i] = (short)f2b(p[i]);
  return r;
}

// async global->LDS, 16B per lane. LDS dest is wave-uniform base + lane*16.
__device__ __forceinline__ void gload16(const u16* g, u16* lds_wave_base) {
  __builtin_amdgcn_global_load_lds(
      (const __attribute__((address_space(1))) u32*)g,
      (__attribute__((address_space(3))) u32*)lds_wave_base, 16, 0, 0);
}

// =====================================================================
// Generic NT GEMM: C[M,N] = A[M,K] * Bt[N,K]^T, fp32 accum, bf16 MFMA.
// 128x128 C-tile, BK=32, 256 thr = 4 waves.
//
// bf16 path (AF32=0): counted-vmcnt double-buffered pipeline.
//   Rounds 2/4 showed both reg-staging and gload_lds are equally bound
//   (~1500 cy/K-step) because the loads were drained to vmcnt(0) inside
//   the same K-step (__syncthreads lowers to vmcnt(0)+barrier). Fix:
//   2 LDS buffers; stage tile t+2 after computing tile t; the per-iter
//   wait is s_waitcnt vmcnt(4) — the NEXT tile's 4 loads stay in flight
//   across the barrier (T4: never drain to 0 in the main loop).
//   Raw s_barrier (not __syncthreads) so the compiler doesn't re-insert
//   the drain; asm memory clobbers + sched_barrier(0) pin ordering.
//   Read-safety: all 8 ds_reads retire before the last MFMA issues
//   (compiler lgkmcnt), so post-MFMA barrier => overwrite of buf is safe.
//   Barrier safety: control flow is fully wave-uniform (template consts,
//   uniform nt), so barrier counts match across waves.
//
// AF32=1 (A is f32, converted in reg staging): round-2 structure kept.
//
// EPI 0: C = bf16(acc)
// EPI 1: C = bf16(exp2(clamp(acc*expscale))); atomicAdd row sums into rowsum
// EPI 2: C = bf16(acc / rowsum[row] + Q[row,col])
// EPI 3: like EPI 0 but gate columns interleaved for the scan:
//        col<1024 unchanged; f_d (1024+d) -> 1024+2d ; r_d (2048+d) -> 1025+2d
// =====================================================================
template<int EPI, int AF32>
__global__ __launch_bounds__(256)
void gemm_nt(const void* __restrict__ Av, int lda, int a_boff,
             const u16* __restrict__ Bt, int ldb, int b_boff,
             u16* __restrict__ C, int ldc, int c_boff,
             int K,
             float* __restrict__ rowsum, int rs_boff,
             const u16* __restrict__ Q, int ldq, int q_boff,
             float expscale)
{
  // two buffers of 128x32 u16 each for A and B
  __shared__ __align__(16) u16 As[2 * 4096];
  __shared__ __align__(16) u16 Bs[2 * 4096];
  const int z = blockIdx.z;
  Bt += (size_t)z * b_boff;
  C  += (size_t)z * c_boff;
  const int row0 = blockIdx.x * 128;
  const int col0 = blockIdx.y * 128;
  const int t = threadIdx.x;
  const int lane = t & 63, wave = t >> 6;
  const int wm = (wave >> 1) * 64, wn = (wave & 1) * 64;
  const int quad = lane >> 4, lrow = lane & 15;

  f32x4 acc[4][4] = {};

  const size_t a_base = (size_t)z * a_boff + (size_t)(row0 + (t >> 2)) * lda + (t & 3) * 8;
  const float* Agf = (const float*)Av + a_base;   // valid when AF32
  const u16*   Agh = (const u16*)Av + a_base;     // valid when !AF32
  const u16* Bg = Bt + (size_t)(col0 + (t >> 2)) * ldb + (t & 3) * 8;
  const size_t a64 = (size_t)64 * lda, b64 = (size_t)64 * ldb;

  if constexpr (!AF32) {
    // ---- counted-vmcnt double-buffered pipeline ----
    const int nt = K >> 5;
    u16* AsW = As + wave * 512;    // wave-uniform staging base, buffer 0
    u16* BsW = Bs + wave * 512;
    auto stage = [&](int buf, int s) {
      const u16* a = Agh + (size_t)s * 32;
      const u16* b = Bg  + (size_t)s * 32;
      u16* aw = AsW + buf * 4096;
      u16* bw = BsW + buf * 4096;
      gload16(a,       aw);
      gload16(a + a64, aw + 2048);
      gload16(b,       bw);
      gload16(b + b64, bw + 2048);
    };
    stage(0, 0);
    stage(1, 1);
    for (int kt = 0; kt < nt; ++kt) {
      const int cur = kt & 1;
      if (kt < nt - 1) {
        asm volatile("s_waitcnt vmcnt(4)" ::: "memory");   // cur tile landed; next stays in flight
      } else {
        asm volatile("s_waitcnt vmcnt(0)" ::: "memory");   // last tile: nothing younger
      }
      __builtin_amdgcn_sched_barrier(0);
      __builtin_amdgcn_s_barrier();                        // all waves' stages landed
      const u16* Ab = As + cur * 4096;
      const u16* Bb = Bs + cur * 4096;
      short8 af[4], bfr[4];
      #pragma unroll
      for (int i = 0; i < 4; i++)
        af[i] = *(const short8*)(Ab + (wm + i * 16 + lrow) * 32 + quad * 8);
      #pragma unroll
      for (int j = 0; j < 4; j++)
        bfr[j] = *(const short8*)(Bb + (wn + j * 16 + lrow) * 32 + quad * 8);
      #pragma unroll
      for (int i = 0; i < 4; i++)
        #pragma unroll
        for (int j = 0; j < 4; j++)
          acc[i][j] = __builtin_amdgcn_mfma_f32_16x16x32_bf16(af[i], bfr[j], acc[i][j], 0, 0, 0);
      asm volatile("" ::: "memory");
      __builtin_amdgcn_sched_barrier(0);
      __builtin_amdgcn_s_barrier();                        // all waves done reading buf[cur]
      if (kt + 2 < nt) stage(cur, kt + 2);                 // overwrite now safe
    }
  } else {
    // ---- reg-staged path for f32 A (round-2 structure) ----
    u16* AsP = As + t * 8;
    u16* BsP = Bs + t * 8;
    const u16* BgP = Bg;
    const float* AgfP = Agf;
    for (int k0 = 0; k0 < K; k0 += 32) {
      short8 ta0 = ld8f(AgfP);
      short8 ta1 = ld8f(AgfP + a64);
      AgfP += 32;
      short8 tb0 = *(const short8*)BgP;
      short8 tb1 = *(const short8*)(BgP + b64);
      BgP += 32;
      __syncthreads();               // prev iteration's LDS reads complete
      *(short8*)AsP = ta0;
      *(short8*)(AsP + 2048) = ta1;
      *(short8*)BsP = tb0;
      *(short8*)(BsP + 2048) = tb1;
      __syncthreads();               // LDS tiles visible to all waves
      short8 af[4], bfr[4];
      #pragma unroll
      for (int i = 0; i < 4; i++)
        af[i] = *(const short8*)(As + (wm + i * 16 + lrow) * 32 + quad * 8);
      #pragma unroll
      for (int j = 0; j < 4; j++)
        bfr[j] = *(const short8*)(Bs + (wn + j * 16 + lrow) * 32 + quad * 8);
      #pragma unroll
      for (int i = 0; i < 4; i++)
        #pragma unroll
        for (int j = 0; j < 4; j++)
          acc[i][j] = __builtin_amdgcn_mfma_f32_16x16x32_bf16(af[i], bfr[j], acc[i][j], 0, 0, 0);
    }
  }

  // ---- epilogue. C/D layout: col = lane&15 (N side), row = quad*4 + reg (M side) ----
  if (EPI == 0) {
    #pragma unroll
    for (int i = 0; i < 4; i++)
      #pragma unroll
      for (int r = 0; r < 4; r++) {
        size_t grow = (size_t)(row0 + wm + i * 16 + quad * 4 + r) * ldc;
        #pragma unroll
        for (int j = 0; j < 4; j++)
          C[grow + col0 + wn + j * 16 + lrow] = f2b(acc[i][j][r]);
      }
  } else if (EPI == 1) {
    #pragma unroll
    for (int i = 0; i < 4; i++)
      #pragma unroll
      for (int r = 0; r < 4; r++) {
        int lr = row0 + wm + i * 16 + quad * 4 + r;
        size_t grow = (size_t)lr * ldc;
        float s = 0.f;
        #pragma unroll
        for (int j = 0; j < 4; j++) {
          float aa = acc[i][j][r] * expscale;
          aa = fminf(fmaxf(aa, -30.f), 30.f);
          float e = exp2f(aa);
          C[grow + col0 + wn + j * 16 + lrow] = f2b(e);
          s += e;
        }
        s += __shfl_xor(s, 1, 64);
        s += __shfl_xor(s, 2, 64);
        s += __shfl_xor(s, 4, 64);
        s += __shfl_xor(s, 8, 64);
        if (lrow == 0) atomicAdd(&rowsum[(size_t)z * rs_boff + lr], s);
      }
  } else if (EPI == 2) {
    const float* rs = rowsum + (size_t)z * rs_boff;
    const u16* Qb = Q + (size_t)z * q_boff;
    #pragma unroll
    for (int i = 0; i < 4; i++)
      #pragma unroll
      for (int r = 0; r < 4; r++) {
        int lr = row0 + wm + i * 16 + quad * 4 + r;
        float inv = 1.0f / rs[lr];
        size_t growc = (size_t)lr * ldc;
        size_t growq = (size_t)lr * ldq;
        #pragma unroll
        for (int j = 0; j < 4; j++) {
          int gcol = col0 + wn + j * 16 + lrow;
          float v = acc[i][j][r] * inv + b2f(Qb[growq + gcol]);
          C[growc + gcol] = f2b(v);
        }
      }
  } else {  // EPI == 3: gate-interleaved store for scan
    #pragma unroll
    for (int i = 0; i < 4; i++)
      #pragma unroll
      for (int r = 0; r < 4; r++) {
        size_t grow = (size_t)(row0 + wm + i * 16 + quad * 4 + r) * ldc;
        #pragma unroll
        for (int j = 0; j < 4; j++) {
          int gcol = col0 + wn + j * 16 + lrow;
          // tile is entirely on one side of 1024 (col0 multiple of 128), branch is uniform
          int ocol = gcol < 1024 ? gcol
                                 : 1024 + 2 * (gcol & 1023) + ((gcol >> 10) - 1);
          C[grow + ocol] = f2b(acc[i][j][r]);
        }
      }
  }
}

// =====================================================================
// Tiled transpose for weights: f32 in -> bf16 out, 64x64 tiles.
// =====================================================================
__global__ __launch_bounds__(256)
void transpose_f32_bf16(const float* __restrict__ in, int instride,
                        u16* __restrict__ out, int outstride)
{
  __shared__ u16 tile[64][66];
  const int r0 = blockIdx.x * 64, c0 = blockIdx.y * 64;
  const int tx = threadIdx.x & 63, ty = threadIdx.x >> 6;
  #pragma unroll
  for (int i = 0; i < 64; i += 4)
    tile[ty + i][tx] = f2b(in[(size_t)(r0 + ty + i) * instride + c0 + tx]);
  __syncthreads();
  #pragma unroll
  for (int i = 0; i < 64; i += 4)
    out[(size_t)(c0 + ty + i) * outstride + r0 + tx] = tile[tx][ty + i];
}

// =====================================================================
// Sequential SRU highway scan over L. One thread per (b,d) chain.
// U: bf16 [L*B, 3072] = [x_tilde(1024) | gates interleaved f0,r0,f1,r1,...]
// X,v,b,out: f32.
// 256 blocks x 64 thr: 1 wave per CU on all 256 CUs. PF=16 register FIFO,
// 4 vmem ops/iter -> consume-wait = vmcnt(61), expressible (max 63).
// =====================================================================
__global__ __launch_bounds__(64)
void scan_kernel(const u16* __restrict__ U, const float* __restrict__ X,
                 const float* __restrict__ V, const float* __restrict__ Bv,
                 float* __restrict__ out)
{
  const int idx = blockIdx.x * 64 + threadIdx.x;  // 0..16383
  const int d = idx & 1023, b = idx >> 10;
  const float nl2e = -1.4426950408889634f;
  const float vf = V[d],  vr = V[1024 + d];
  const float bf_ = Bv[d], br_ = Bv[1024 + d];
  const float pvf = nl2e * vf, pvr = nl2e * vr;

  constexpr int PF = 16;                 // prefetch depth (iterations)
  const size_t ustep = 16 * 3072;        // u16 elements per l-step
  const size_t gstep = 16 * 1536;        // u32 elements per l-step
  const size_t xstep = 16 * 1024;        // f32 elements per l-step

  const u16*  Uxt = U + (size_t)b * 3072 + d;                 // x_tilde
  const u32*  Ug  = (const u32*)(U + (size_t)b * 3072 + 1024) + d;  // (f,r) pair
  const float* Xp = X + (size_t)b * 1024 + d;
  float*       Op = out + (size_t)b * 1024 + d;

  u16 pxt[PF]; u32 pg[PF]; float pxr[PF];
  #pragma unroll
  for (int p = 0; p < PF; p++) {
    pxt[p] = Uxt[0];
    pg[p]  = Ug[0];
    pxr[p] = Xp[0];
    Uxt += ustep; Ug += gstep; Xp += xstep;
  }

  float c = 0.f;
  for (int l0 = 0; l0 < 2048 - PF; l0 += PF) {
    #pragma unroll
    for (int p = 0; p < PF; p++) {
      // consume slot p (iteration l0+p)
      float xt = b2f(pxt[p]);
      u32 g = pg[p];
      float fr = b2f((u16)(g & 0xffffu));
      float rr = b2f((u16)(g >> 16));
      float xr = pxr[p];
      // refill slot p (iteration l0+p+PF)
      pxt[p] = Uxt[0];
      pg[p]  = Ug[0];
      pxr[p] = Xp[0];
      Uxt += ustep; Ug += gstep; Xp += xstep;
      // gates: sigmoid(a) = rcp(1 + exp2(-log2e * a)); bias folded off-chain
      float ef = __builtin_amdgcn_exp2f(fmaf(pvf, c, nl2e * (fr + bf_)));
      float er = __builtin_amdgcn_exp2f(fmaf(pvr, c, nl2e * (rr + br_)));
      float fg = __builtin_amdgcn_rcpf(1.f + ef);
      float rg = __builtin_amdgcn_rcpf(1.f + er);
      c = fg * (c - xt) + xt;            // f*c + (1-f)*x_tilde
      float h = rg * (c - xr) + xr;      // r*c_new + (1-r)*x
      Op[0] = h; Op += xstep;
      __builtin_amdgcn_sched_barrier(0); // keep bodies in program order
    }
  }
  // tail: last PF iterations, compute-only (no OOB prefetch)
  #pragma unroll
  for (int p = 0; p < PF; p++) {
    float xt = b2f(pxt[p]);
    u32 g = pg[p];
    float fr = b2f((u16)(g & 0xffffu));
    float rr = b2f((u16)(g >> 16));
    float xr = pxr[p];
    float ef = __builtin_amdgcn_exp2f(fmaf(pvf, c, nl2e * (fr + bf_)));
    float er = __builtin_amdgcn_exp2f(fmaf(pvr, c, nl2e * (rr + br_)));
    float fg = __builtin_amdgcn_rcpf(1.f + ef);
    float rg = __builtin_amdgcn_rcpf(1.f + er);
    c = fg * (c - xt) + xt;
    float h = rg * (c - xr) + xr;
    Op[0] = h; Op += xstep;
  }
}

// =====================================================================
// Workspace layout (bytes) — total 240,254,976 B (~229.1 MB):
//  E    @ 0           134,217,728  bf16 [B,2048,2048]   } U aliases 0..192MB
//  q    @ 134,217,728  33,554,432  bf16 [32768,512]     } (all dead by U-GEMM)
//  vat  @ 167,772,160  33,554,432  bf16 [B,512,2048]    }
//  k    @ 201,326,592  33,554,432  bf16 [32768,512] (dead after E-GEMM)
//  ctxq @ 201,326,592  33,554,432  aliases k; outside U region
//  rsum @ 234,881,024     131,072  fp32 [B,2048]
//  W1t  @ 235,012,096   1,048,576  bf16 [512,1024]
//  W2t  @ 236,060,672   1,048,576  bf16 [1024,512]
//  W3t  @ 237,109,248   3,145,728  bf16 [3072,512]
//  U    @ 0           201,326,592  bf16 [32768,3072] (gate-interleaved)
// =====================================================================
extern "C" void kernel_launch(void* const* d_in, const int* in_sizes, int n_in,
                              void* d_out, int out_size, void* d_ws, size_t ws_size,
                              hipStream_t stream) {
  const float* x  = (const float*)d_in[0];
  const float* W1 = (const float*)d_in[1];
  const float* W2 = (const float*)d_in[2];
  const float* W3 = (const float*)d_in[3];
  const float* v  = (const float*)d_in[4];
  const float* bb = (const float*)d_in[5];
  float* out = (float*)d_out;
  char* ws = (char*)d_ws;

  u16*   E      = (u16*)(ws + 0);
  u16*   q      = (u16*)(ws + 134217728);
  u16*   vat    = (u16*)(ws + 167772160);
  u16*   kbuf   = (u16*)(ws + 201326592);
  u16*   ctxq   = (u16*)(ws + 201326592);  // aliases kbuf (dead by then)
  float* rowsum = (float*)(ws + 234881024);
  u16*   W1t    = (u16*)(ws + 235012096);
  u16*   W2t    = (u16*)(ws + 236060672);
  u16*   W3t    = (u16*)(ws + 237109248);
  u16*   U      = (u16*)(ws + 0);          // aliases E/q/vat (dead by then)

  hipMemsetAsync(rowsum, 0, 131072, stream);

  const dim3 blk(256);
  // weight transposes: W[K,N] f32 -> Wt[N,K] bf16 for NT GEMM
  transpose_f32_bf16<<<dim3(16, 8),  blk, 0, stream>>>(W1, 512,  W1t, 1024);
  transpose_f32_bf16<<<dim3(8, 16),  blk, 0, stream>>>(W2, 1024, W2t, 512);
  transpose_f32_bf16<<<dim3(8, 48),  blk, 0, stream>>>(W3, 3072, W3t, 512);

  // q = x @ W1 : M=32768 K=1024 N=512 (A is f32, converted in reg staging)
  gemm_nt<0, 1><<<dim3(256, 4, 1), blk, 0, stream>>>(x, 1024, 0, W1t, 1024, 0,
                                                     q, 512, 0, 1024,
                                                     nullptr, 0, nullptr, 0, 0, 0.f);
  // k = q @ W2[:, :512] : M=32768 K=512 N=512  (W2t rows 0..511)
  gemm_nt<0, 0><<<dim3(256, 4, 1), blk, 0, stream>>>(q, 512, 0, W2t, 512, 0,
                                                     kbuf, 512, 0, 512,
                                                     nullptr, 0, nullptr, 0, 0, 0.f);
  // vat_b[p][l] = sum_k W2t[512+p][k] * q_b[l][k]  (va^T, built transposed for free)
  // M=512 N=2048 K=512, z=B
  gemm_nt<0, 0><<<dim3(4, 16, 16), blk, 0, stream>>>(W2t + 262144, 512, 0, q, 8192, 512,
                                                     vat, 2048, 1048576, 512,
                                                     nullptr, 0, nullptr, 0, 0, 0.f);
  // E = exp(q_b @ k_b^T * scale), rowsum accumulated. M=N=2048 K=512, z=B
  const float expscale = 0.044194173824159216f * 1.4426950408889634f; // (1/sqrt(512))*log2(e)
  gemm_nt<1, 0><<<dim3(16, 16, 16), blk, 0, stream>>>(q, 8192, 512, kbuf, 8192, 512,
                                                      E, 2048, 4194304, 512,
                                                      rowsum, 2048, nullptr, 0, 0, expscale);
  // ctxq = E_b @ vat_b^T / rowsum + q : M=2048 N=512 K=2048, z=B
  gemm_nt<2, 0><<<dim3(16, 4, 16), blk, 0, stream>>>(E, 2048, 4194304, vat, 2048, 1048576,
                                                     ctxq, 8192, 512, 2048,
                                                     rowsum, 2048, q, 8192, 512, 0.f);
  // U = ctxq @ W3 : M=32768 K=512 N=3072, gate-interleaved store for scan
  gemm_nt<3, 0><<<dim3(256, 24, 1), blk, 0, stream>>>(ctxq, 512, 0, W3t, 512, 0,
                                                      U, 3072, 0, 512,
                                                      nullptr, 0, nullptr, 0, 0, 0.f);
  // highway recurrence: 256 blocks x 64 thr = 1 wave on each of 256 CUs
  scan_kernel<<<dim3(256, 1, 1), dim3(64), 0, stream>>>(U, x, v, bb, out);
}